// Round 1
// baseline (672.583 us; speedup 1.0000x reference)
//
#include <hip/hip_runtime.h>

// ---------------------------------------------------------------------------
// GCN pipeline: CNN(conv3x3+relu+pool2x2+FC1+FC2) -> SAGE(mean) -> SAGE(mean)
// Round 0: fp32 correctness-first baseline.
//   - cnn_fused: 8 nodes/block, w1 staged per half-channel in LDS, pooled in
//     registers, FC1 accumulated in 32 VGPRs, LDS reduce, FC2 epilogue.
//   - SAGE via float atomics; layer2 uses linearity: scatter z=h1@s2_neigh
//     (10-dim) instead of h1 (64-dim).
// ---------------------------------------------------------------------------

#define NB 8  // nodes per block in cnn_fused

__global__ __launch_bounds__(256) void zero_ws(float* __restrict__ ws, int count) {
    int i = blockIdx.x * 256 + threadIdx.x;
    if (i < count) ws[i] = 0.0f;
}

// LDS: in_s 8*1453*4 = 46496 B  (padded [22][66] per node, +1 float pad -> stride 1453, coprime with 32 banks)
//      w1c 160*36*4  = 23040 B  (half-channel chunk of w1, row stride 36 -> 16B aligned + conflict-free)
//      h1s 8*32*4    =  1024 B
// total 70560 B -> 2 blocks/CU (141 KB of 160 KB), 8 waves/CU.
__global__ __launch_bounds__(256) void cnn_fused(
    const float* __restrict__ feat,
    const float* __restrict__ conv_w, const float* __restrict__ conv_b,
    const float* __restrict__ w1, const float* __restrict__ b1,
    const float* __restrict__ w2, const float* __restrict__ b2,
    float* __restrict__ h_out, int N)
{
    __shared__ float in_s[NB * 1453];
    __shared__ float w1c[160 * 36];
    __shared__ float h1s[NB * 32];

    const int t = threadIdx.x;
    const int base = blockIdx.x * NB;

    // zero padded input halo, then load the 20x64 tiles
    for (int i = t; i < NB * 1453; i += 256) in_s[i] = 0.0f;
    __syncthreads();
    for (int nn = 0; nn < NB; ++nn) {
        if (base + nn < N) {
            const float* fp = feat + (size_t)(base + nn) * 1280;
            for (int i = t; i < 1280; i += 256) {
                int h = i >> 6, w = i & 63;
                in_s[nn * 1453 + (h + 1) * 66 + (w + 1)] = fp[i];
            }
        }
    }

    const int n  = t & 7;   // node within block
    const int ig = t >> 3;  // 0..31 : pooled-position group

    float acc[32];
#pragma unroll
    for (int j = 0; j < 32; ++j) acc[j] = 0.0f;

    for (int hc = 0; hc < 64; ++hc) {   // 32 channels x 2 halves (160 pooled pos each)
        const int c = hc >> 1;
        const int half = hc & 1;
        __syncthreads();   // protect w1c from previous iteration's readers
        // stage w1 rows [hc*160 .. hc*160+159] -> w1c (float4 both sides)
        for (int idx = t; idx < 1280; idx += 256) {  // 1280 float4 = 5120 floats
            float4 v = ((const float4*)w1)[hc * 1280 + idx];
            int i  = idx >> 3;   // row (8 float4 per row of 32)
            int j4 = idx & 7;
            *((float4*)&w1c[i * 36 + j4 * 4]) = v;
        }
        const float cw0 = conv_w[c*9+0], cw1 = conv_w[c*9+1], cw2 = conv_w[c*9+2];
        const float cw3 = conv_w[c*9+3], cw4 = conv_w[c*9+4], cw5 = conv_w[c*9+5];
        const float cw6 = conv_w[c*9+6], cw7 = conv_w[c*9+7], cw8 = conv_w[c*9+8];
        const float cb  = conv_b[c];
        __syncthreads();

#pragma unroll
        for (int q = 0; q < 5; ++q) {
            const int il = ig * 5 + q;        // 0..159 within chunk
            const int p  = half * 160 + il;   // pooled pos within channel (0..319)
            const int ph = p >> 5, pw = p & 31;
            const float* ip = &in_s[n * 1453 + (2 * ph) * 66 + (2 * pw)];
            // 4x4 padded-input region feeding the 2x2 conv outputs
            float r00=ip[0],   r01=ip[1],   r02=ip[2],   r03=ip[3];
            float r10=ip[66],  r11=ip[67],  r12=ip[68],  r13=ip[69];
            float r20=ip[132], r21=ip[133], r22=ip[134], r23=ip[135];
            float r30=ip[198], r31=ip[199], r32=ip[200], r33=ip[201];
            float s00 = cb + cw0*r00+cw1*r01+cw2*r02 + cw3*r10+cw4*r11+cw5*r12 + cw6*r20+cw7*r21+cw8*r22;
            float s01 = cb + cw0*r01+cw1*r02+cw2*r03 + cw3*r11+cw4*r12+cw5*r13 + cw6*r21+cw7*r22+cw8*r23;
            float s10 = cb + cw0*r10+cw1*r11+cw2*r12 + cw3*r20+cw4*r21+cw5*r22 + cw6*r30+cw7*r31+cw8*r32;
            float s11 = cb + cw0*r11+cw1*r12+cw2*r13 + cw3*r21+cw4*r22+cw5*r23 + cw6*r31+cw7*r32+cw8*r33;
            // relu(maxpool) == max(conv outs, 0)
            float m = fmaxf(fmaxf(fmaxf(s00, s01), fmaxf(s10, s11)), 0.0f);
            const float* wr = &w1c[il * 36];
#pragma unroll
            for (int j = 0; j < 32; ++j) acc[j] = fmaf(m, wr[j], acc[j]);
        }
    }

    // reduce partial FC1 sums across the 32 ig-groups (overlay red on in_s)
    __syncthreads();
    float* red = in_s;  // needs 256*32*4 = 32 KB <= 46.5 KB
#pragma unroll
    for (int j = 0; j < 32; ++j) red[ig * 256 + n * 32 + j] = acc[j];
    __syncthreads();

    const int n2 = t >> 5;   // 0..7
    const int j2 = t & 31;
    float s = 0.0f;
#pragma unroll
    for (int g = 0; g < 32; ++g) s += red[g * 256 + n2 * 32 + j2];
    s = fmaxf(s + b1[j2], 0.0f);
    h1s[n2 * 32 + j2] = s;
    __syncthreads();

    float o = b2[j2];
#pragma unroll
    for (int j = 0; j < 32; ++j) o = fmaf(h1s[n2 * 32 + j], w2[j * 32 + j2], o);
    o = fmaxf(o, 0.0f);
    const int node = base + n2;
    if (node < N) h_out[node * 32 + j2] = o;
}

__global__ __launch_bounds__(256) void scatter_deg_agg1(
    const int* __restrict__ src, const int* __restrict__ dst,
    const float* __restrict__ h, float* __restrict__ agg1, float* __restrict__ deg, int E)
{
    int tid = blockIdx.x * 256 + threadIdx.x;
    int e = tid >> 5, j = tid & 31;
    if (e >= E) return;
    int s = src[e], d = dst[e];
    atomicAdd(&agg1[d * 32 + j], h[s * 32 + j]);
    if (j == 0) atomicAdd(&deg[d], 1.0f);
}

__global__ __launch_bounds__(256) void sage1_finish(
    const float* __restrict__ h, const float* __restrict__ agg1, const float* __restrict__ deg,
    const float* __restrict__ s1_self, const float* __restrict__ s1_neigh,
    const float* __restrict__ s1_b, float* __restrict__ h1, int N)
{
    int tid = blockIdx.x * 256 + threadIdx.x;
    int n = tid >> 6, k = tid & 63;
    if (n >= N) return;
    float inv = 1.0f / fmaxf(deg[n], 1.0f);
    float o = s1_b[k];
#pragma unroll
    for (int j = 0; j < 32; ++j) {
        o = fmaf(h[n * 32 + j], s1_self[j * 64 + k], o);
        o = fmaf(agg1[n * 32 + j] * inv, s1_neigh[j * 64 + k], o);
    }
    h1[n * 64 + k] = fmaxf(o, 0.0f);
}

// z = h1 @ s2_neigh  (mean-agg commutes with the matmul, so scatter 10-dim z)
__global__ __launch_bounds__(256) void sage2_z(
    const float* __restrict__ h1, const float* __restrict__ s2_neigh,
    float* __restrict__ z, int N)
{
    int tid = blockIdx.x * 256 + threadIdx.x;
    int n = tid >> 4, k = tid & 15;
    if (n >= N || k >= 10) return;
    float o = 0.0f;
#pragma unroll
    for (int j = 0; j < 64; ++j) o = fmaf(h1[n * 64 + j], s2_neigh[j * 10 + k], o);
    z[n * 10 + k] = o;
}

__global__ __launch_bounds__(256) void scatter_agg2(
    const int* __restrict__ src, const int* __restrict__ dst,
    const float* __restrict__ z, float* __restrict__ agg2, int E)
{
    int tid = blockIdx.x * 256 + threadIdx.x;
    int e = tid >> 4, k = tid & 15;
    if (e >= E || k >= 10) return;
    atomicAdd(&agg2[dst[e] * 10 + k], z[src[e] * 10 + k]);
}

__global__ __launch_bounds__(256) void sage2_final(
    const float* __restrict__ h1, const float* __restrict__ agg2, const float* __restrict__ deg,
    const float* __restrict__ s2_self, const float* __restrict__ s2_b,
    float* __restrict__ out, int N)
{
    int tid = blockIdx.x * 256 + threadIdx.x;
    int n = tid >> 4, k = tid & 15;
    if (n >= N || k >= 10) return;
    float inv = 1.0f / fmaxf(deg[n], 1.0f);
    float o = s2_b[k] + agg2[n * 10 + k] * inv;
#pragma unroll
    for (int j = 0; j < 64; ++j) o = fmaf(h1[n * 64 + j], s2_self[j * 10 + k], o);
    out[n * 10 + k] = o;
}

extern "C" void kernel_launch(void* const* d_in, const int* in_sizes, int n_in,
                              void* d_out, int out_size, void* d_ws, size_t ws_size,
                              hipStream_t stream)
{
    const float* feat     = (const float*)d_in[0];
    const int*   src      = (const int*)d_in[1];
    const int*   dst      = (const int*)d_in[2];
    const float* conv_w   = (const float*)d_in[3];
    const float* conv_b   = (const float*)d_in[4];
    const float* w1       = (const float*)d_in[5];
    const float* b1       = (const float*)d_in[6];
    const float* w2       = (const float*)d_in[7];
    const float* b2       = (const float*)d_in[8];
    const float* s1_self  = (const float*)d_in[9];
    const float* s1_neigh = (const float*)d_in[10];
    const float* s1_b     = (const float*)d_in[11];
    const float* s2_self  = (const float*)d_in[12];
    const float* s2_neigh = (const float*)d_in[13];
    const float* s2_b     = (const float*)d_in[14];
    float* out = (float*)d_out;

    const int N = in_sizes[0] / 1280;  // 10000
    const int E = in_sizes[1];         // 320000

    // workspace layout (floats): deg | agg1 | agg2 | h_cnn | h1 | z  = 1.49 Mf = 5.96 MB
    float* ws    = (float*)d_ws;
    float* deg   = ws;
    float* agg1  = deg + N;
    float* agg2  = agg1 + (size_t)N * 32;
    float* h_cnn = agg2 + (size_t)N * 10;
    float* h1    = h_cnn + (size_t)N * 32;
    float* z     = h1 + (size_t)N * 64;

    const int zcount = N * 43;  // deg + agg1 + agg2 (contiguous)
    zero_ws<<<(zcount + 255) / 256, 256, 0, stream>>>(ws, zcount);

    cnn_fused<<<(N + NB - 1) / NB, 256, 0, stream>>>(feat, conv_w, conv_b, w1, b1, w2, b2, h_cnn, N);

    scatter_deg_agg1<<<(int)(((size_t)E * 32 + 255) / 256), 256, 0, stream>>>(src, dst, h_cnn, agg1, deg, E);
    sage1_finish<<<(int)(((size_t)N * 64 + 255) / 256), 256, 0, stream>>>(h_cnn, agg1, deg, s1_self, s1_neigh, s1_b, h1, N);

    sage2_z<<<(int)(((size_t)N * 16 + 255) / 256), 256, 0, stream>>>(h1, s2_neigh, z, N);
    scatter_agg2<<<(int)(((size_t)E * 16 + 255) / 256), 256, 0, stream>>>(src, dst, z, agg2, E);
    sage2_final<<<(int)(((size_t)N * 16 + 255) / 256), 256, 0, stream>>>(h1, agg2, deg, s2_self, s2_b, out, N);
}

// Round 2
// 452.232 us; speedup vs baseline: 1.4873x; 1.4873x over previous
//
#include <hip/hip_runtime.h>

// ---------------------------------------------------------------------------
// GCN pipeline: CNN(conv3x3+relu+pool2x2+FC1+FC2) -> SAGE(mean) -> SAGE(mean)
// Round 2: conv in registers (input shared across channels), FC1 via
// split-bf16 MFMA (hi/lo, 3 mfma/step ~ fp32 accuracy), w1 pre-packed into
// fragment-ready swizzled chunk images by a prep kernel.
// ---------------------------------------------------------------------------

typedef __attribute__((ext_vector_type(8))) short bf16x8;
typedef __attribute__((ext_vector_type(4))) float f32x4;

__device__ __forceinline__ unsigned short f2bf(float v) {
    union { float f; unsigned int u; } x; x.f = v;
    unsigned int r = x.u + 0x7FFFu + ((x.u >> 16) & 1u);  // RNE
    return (unsigned short)(r >> 16);
}
__device__ __forceinline__ float bf2f(unsigned short b) {
    union { float f; unsigned int u; } x; x.u = ((unsigned int)b) << 16;
    return x.f;
}

__global__ __launch_bounds__(256) void zero_ws(float* __restrict__ ws, int count) {
    int i = blockIdx.x * 256 + threadIdx.x;
    if (i < count) ws[i] = 0.0f;
}

// ---------------------------------------------------------------------------
// w1 prep: repack w1 [10240][32] f32 into 40 chunk-images, each 32KB:
//   chunk (ph, cq): [hi 16KB][lo 16KB], image byte = j*512 + ((kl*2)^((j&7)<<4))
//   where kl = (c&7)*32 + pw, row = c*320 + ph*32 + pw, c = cq*8 + (kl>>5).
// grid: 40 blocks (one per chunk) x 256 threads.
// ---------------------------------------------------------------------------
__global__ __launch_bounds__(256) void w1_prep(
    const float* __restrict__ w1, unsigned char* __restrict__ w1t)
{
    const int chunk = blockIdx.x;          // 0..39
    const int ph = chunk >> 2, cq = chunk & 3;
    const int t = threadIdx.x;
    const int j = t & 31, seg = t >> 5;    // seg = cc (0..7)
    const int c = cq * 8 + seg;
    const unsigned int swz = ((unsigned)(j & 7)) << 4;
    unsigned char* baseb = w1t + (size_t)chunk * 32768 + j * 512;

#pragma unroll
    for (int i = 0; i < 32; i += 2) {
        int row0 = c * 320 + ph * 32 + i;
        float v0 = w1[(size_t)row0 * 32 + j];
        float v1 = w1[(size_t)(row0 + 1) * 32 + j];
        unsigned short h0 = f2bf(v0), h1 = f2bf(v1);
        unsigned short l0 = f2bf(v0 - bf2f(h0)), l1 = f2bf(v1 - bf2f(h1));
        unsigned int byt = ((unsigned)(seg * 64 + 2 * i)) ^ swz;  // 4-aligned
        *(unsigned int*)(baseb + byt)         = ((unsigned)h1 << 16) | h0;
        *(unsigned int*)(baseb + 16384 + byt) = ((unsigned)l1 << 16) | l0;
    }
}

// ---------------------------------------------------------------------------
// Fused CNN: 16 nodes/block, 256 threads (4 waves).
// Per (ph 0..9, cq 0..3) chunk of K=256 (8 channels x 32 pooled cols):
//   - prefetch B chunk image (32KB) to regs (coalesced uint4)
//   - conv+pool in registers (thread = (n = t&15, tc = t>>4), 2 pooled cols,
//     8 channels), write pooled hi/lo bf16 to swizzled A tiles
//   - write B regs to LDS linear
//   - barrier; each wave: 2 K-steps x 2 j-halves x 3 split-MFMAs; barrier
// Epilogue: cross-wave reduce, +b1, relu, FC2(+b2), relu -> h_out.
// LDS: Ah 8K + Al 8K + Bb 32K + red 8K + h1s 2K = 58KB -> 2 blocks/CU.
// ---------------------------------------------------------------------------
__global__ __launch_bounds__(256, 2) void cnn_fused_v3(
    const float* __restrict__ feat,
    const float* __restrict__ conv_w, const float* __restrict__ conv_b,
    const unsigned char* __restrict__ w1t, const float* __restrict__ b1,
    const float* __restrict__ w2, const float* __restrict__ b2,
    float* __restrict__ h_out)
{
    __shared__ __align__(16) unsigned char Ah[8192];   // [16n][256k] bf16, swizzled
    __shared__ __align__(16) unsigned char Al[8192];
    __shared__ __align__(16) unsigned char Bb[32768];  // [hi 16K][lo 16K], [32j][256k]
    __shared__ float red[4 * 16 * 32];
    __shared__ float h1s[16 * 32];

    const int t = threadIdx.x;
    const int wv = t >> 6;            // wave 0..3
    const int lane = t & 63;
    const int n  = t & 15;            // node within block (fast for A-write banks)
    const int tc = t >> 4;            // pooled col pair 0..15
    const int base = blockIdx.x * 16;
    const float* featn = feat + (size_t)(base + n) * 1280;

    f32x4 acc0 = {0.f, 0.f, 0.f, 0.f};
    f32x4 acc1 = {0.f, 0.f, 0.f, 0.f};

    const unsigned int aswz = ((unsigned)(n & 7)) << 4;
    unsigned char* Ahb = Ah + n * 512;
    unsigned char* Alb = Al + n * 512;

    // MFMA frag addressing (per-lane constants)
    const int fn  = lane & 15;            // A row / B col / D col
    const int fkg = lane >> 4;            // k-group
    const unsigned int fa_swz = ((unsigned)(fn & 7)) << 4;
    const unsigned int fb_swz0 = fa_swz;                       // j = fn      (jh=0)
    const unsigned int fb_swz1 = ((unsigned)((fn + 16) & 7)) << 4;  // j = fn+16: (fn&7) same
    unsigned char* fA_hi = Ah + fn * 512;
    unsigned char* fA_lo = Al + fn * 512;
    unsigned char* fB0 = Bb + fn * 512;           // jh=0 row
    unsigned char* fB1 = Bb + (fn + 16) * 512;    // jh=1 row

    for (int ph = 0; ph < 10; ++ph) {
        // ---- load 4x8 input window into registers (rows 2ph-1..2ph+2, cols 4tc-1..4tc+6)
        float w[4][8];
#pragma unroll
        for (int dr = 0; dr < 4; ++dr) {
            int r = 2 * ph - 1 + dr;
            bool rv = (r >= 0) && (r < 20);
            float4 lo = make_float4(0.f, 0.f, 0.f, 0.f);
            float4 mid = lo, hi = lo;
            if (rv) {
                const float* rowp = featn + r * 64;
                mid = *(const float4*)(rowp + 4 * tc);
                if (tc > 0)  lo = *(const float4*)(rowp + 4 * tc - 4);
                if (tc < 15) hi = *(const float4*)(rowp + 4 * tc + 4);
            }
            w[dr][0] = lo.w;
            w[dr][1] = mid.x; w[dr][2] = mid.y; w[dr][3] = mid.z; w[dr][4] = mid.w;
            w[dr][5] = hi.x;  w[dr][6] = hi.y;  w[dr][7] = hi.z;
        }

        for (int cq = 0; cq < 4; ++cq) {
            const int chunk = ph * 4 + cq;

            // ---- prefetch B chunk (32KB) into regs, coalesced
            const uint4* wsrc = (const uint4*)(w1t + (size_t)chunk * 32768);
            uint4 breg[8];
#pragma unroll
            for (int r = 0; r < 8; ++r) breg[r] = wsrc[t + 256 * r];

            // ---- conv + pool for 8 channels, write A hi/lo (swizzled)
#pragma unroll
            for (int cc = 0; cc < 8; ++cc) {
                const int c = cq * 8 + cc;
                const float* cwp = conv_w + c * 9;   // uniform -> s_load
                float cw0 = cwp[0], cw1 = cwp[1], cw2 = cwp[2];
                float cw3 = cwp[3], cw4 = cwp[4], cw5 = cwp[5];
                float cw6 = cwp[6], cw7 = cwp[7], cw8 = cwp[8];
                float cb = conv_b[c];
                float s[2][4];
#pragma unroll
                for (int a = 0; a < 2; ++a) {
#pragma unroll
                    for (int x = 0; x < 4; ++x) {
                        float acc = cb;
                        acc = fmaf(w[a+0][x+0], cw0, acc);
                        acc = fmaf(w[a+0][x+1], cw1, acc);
                        acc = fmaf(w[a+0][x+2], cw2, acc);
                        acc = fmaf(w[a+1][x+0], cw3, acc);
                        acc = fmaf(w[a+1][x+1], cw4, acc);
                        acc = fmaf(w[a+1][x+2], cw5, acc);
                        acc = fmaf(w[a+2][x+0], cw6, acc);
                        acc = fmaf(w[a+2][x+1], cw7, acc);
                        acc = fmaf(w[a+2][x+2], cw8, acc);
                        s[a][x] = acc;
                    }
                }
                float p0 = fmaxf(fmaxf(fmaxf(s[0][0], s[0][1]), fmaxf(s[1][0], s[1][1])), 0.f);
                float p1 = fmaxf(fmaxf(fmaxf(s[0][2], s[0][3]), fmaxf(s[1][2], s[1][3])), 0.f);
                unsigned short h0 = f2bf(p0), h1 = f2bf(p1);
                unsigned short l0 = f2bf(p0 - bf2f(h0)), l1 = f2bf(p1 - bf2f(h1));
                unsigned int byt = ((unsigned)(cc * 64 + 4 * tc)) ^ aswz;
                *(unsigned int*)(Ahb + byt) = ((unsigned)h1 << 16) | h0;
                *(unsigned int*)(Alb + byt) = ((unsigned)l1 << 16) | l0;
            }

            // ---- write B to LDS (linear)
            uint4* bdst = (uint4*)Bb;
#pragma unroll
            for (int r = 0; r < 8; ++r) bdst[t + 256 * r] = breg[r];

            __syncthreads();

            // ---- MFMA: wave wv handles ksteps {wv, wv+4}
#pragma unroll
            for (int si = 0; si < 2; ++si) {
                const int ks = wv + 4 * si;
                const unsigned int koff = (unsigned)(ks * 64 + fkg * 16);
                bf16x8 a_hi = *(const bf16x8*)(fA_hi + (koff ^ fa_swz));
                bf16x8 a_lo = *(const bf16x8*)(fA_lo + (koff ^ fa_swz));
                bf16x8 b_h0 = *(const bf16x8*)(fB0 + (koff ^ fb_swz0));
                bf16x8 b_l0 = *(const bf16x8*)(fB0 + 16384 + (koff ^ fb_swz0));
                bf16x8 b_h1 = *(const bf16x8*)(fB1 + (koff ^ fb_swz1));
                bf16x8 b_l1 = *(const bf16x8*)(fB1 + 16384 + (koff ^ fb_swz1));
                acc0 = __builtin_amdgcn_mfma_f32_16x16x32_bf16(a_lo, b_h0, acc0, 0, 0, 0);
                acc0 = __builtin_amdgcn_mfma_f32_16x16x32_bf16(a_hi, b_l0, acc0, 0, 0, 0);
                acc0 = __builtin_amdgcn_mfma_f32_16x16x32_bf16(a_hi, b_h0, acc0, 0, 0, 0);
                acc1 = __builtin_amdgcn_mfma_f32_16x16x32_bf16(a_lo, b_h1, acc1, 0, 0, 0);
                acc1 = __builtin_amdgcn_mfma_f32_16x16x32_bf16(a_hi, b_l1, acc1, 0, 0, 0);
                acc1 = __builtin_amdgcn_mfma_f32_16x16x32_bf16(a_hi, b_h1, acc1, 0, 0, 0);
            }

            __syncthreads();
        }
    }

    // ---- cross-wave reduction of partial FC1, bias, relu, FC2, relu
#pragma unroll
    for (int r = 0; r < 4; ++r) {
        int row = (lane >> 4) * 4 + r;   // node
        red[wv * 512 + row * 32 + fn]        = acc0[r];
        red[wv * 512 + row * 32 + 16 + fn]   = acc1[r];
    }
    __syncthreads();

    {
        const int en = t >> 4, jp = t & 15;
        const int j0 = 2 * jp;
        float2 bv = *(const float2*)(b1 + j0);
        float s0 = bv.x, s1 = bv.y;
#pragma unroll
        for (int wi = 0; wi < 4; ++wi) {
            s0 += red[wi * 512 + en * 32 + j0];
            s1 += red[wi * 512 + en * 32 + j0 + 1];
        }
        s0 = fmaxf(s0, 0.f); s1 = fmaxf(s1, 0.f);
        h1s[en * 32 + j0] = s0;
        h1s[en * 32 + j0 + 1] = s1;
    }
    __syncthreads();
    {
        const int en = t >> 4, jp = t & 15;
        const int j0 = 2 * jp;
        float2 bv = *(const float2*)(b2 + j0);
        float o0 = bv.x, o1 = bv.y;
#pragma unroll
        for (int k = 0; k < 32; ++k) {
            float h = h1s[en * 32 + k];
            float2 wv2 = *(const float2*)(w2 + k * 32 + j0);
            o0 = fmaf(h, wv2.x, o0);
            o1 = fmaf(h, wv2.y, o1);
        }
        o0 = fmaxf(o0, 0.f); o1 = fmaxf(o1, 0.f);
        float2 ov = make_float2(o0, o1);
        *(float2*)(h_out + (size_t)(base + en) * 32 + j0) = ov;
    }
}

// --------------------------- SAGE layers (unchanged) -----------------------
__global__ __launch_bounds__(256) void scatter_deg_agg1(
    const int* __restrict__ src, const int* __restrict__ dst,
    const float* __restrict__ h, float* __restrict__ agg1, float* __restrict__ deg, int E)
{
    int tid = blockIdx.x * 256 + threadIdx.x;
    int e = tid >> 5, j = tid & 31;
    if (e >= E) return;
    int s = src[e], d = dst[e];
    atomicAdd(&agg1[d * 32 + j], h[s * 32 + j]);
    if (j == 0) atomicAdd(&deg[d], 1.0f);
}

__global__ __launch_bounds__(256) void sage1_finish(
    const float* __restrict__ h, const float* __restrict__ agg1, const float* __restrict__ deg,
    const float* __restrict__ s1_self, const float* __restrict__ s1_neigh,
    const float* __restrict__ s1_b, float* __restrict__ h1, int N)
{
    int tid = blockIdx.x * 256 + threadIdx.x;
    int nn = tid >> 6, k = tid & 63;
    if (nn >= N) return;
    float inv = 1.0f / fmaxf(deg[nn], 1.0f);
    float o = s1_b[k];
#pragma unroll
    for (int j = 0; j < 32; ++j) {
        o = fmaf(h[nn * 32 + j], s1_self[j * 64 + k], o);
        o = fmaf(agg1[nn * 32 + j] * inv, s1_neigh[j * 64 + k], o);
    }
    h1[nn * 64 + k] = fmaxf(o, 0.0f);
}

__global__ __launch_bounds__(256) void sage2_z(
    const float* __restrict__ h1, const float* __restrict__ s2_neigh,
    float* __restrict__ z, int N)
{
    int tid = blockIdx.x * 256 + threadIdx.x;
    int nn = tid >> 4, k = tid & 15;
    if (nn >= N || k >= 10) return;
    float o = 0.0f;
#pragma unroll
    for (int j = 0; j < 64; ++j) o = fmaf(h1[nn * 64 + j], s2_neigh[j * 10 + k], o);
    z[nn * 10 + k] = o;
}

__global__ __launch_bounds__(256) void scatter_agg2(
    const int* __restrict__ src, const int* __restrict__ dst,
    const float* __restrict__ z, float* __restrict__ agg2, int E)
{
    int tid = blockIdx.x * 256 + threadIdx.x;
    int e = tid >> 4, k = tid & 15;
    if (e >= E || k >= 10) return;
    atomicAdd(&agg2[dst[e] * 10 + k], z[src[e] * 10 + k]);
}

__global__ __launch_bounds__(256) void sage2_final(
    const float* __restrict__ h1, const float* __restrict__ agg2, const float* __restrict__ deg,
    const float* __restrict__ s2_self, const float* __restrict__ s2_b,
    float* __restrict__ out, int N)
{
    int tid = blockIdx.x * 256 + threadIdx.x;
    int nn = tid >> 4, k = tid & 15;
    if (nn >= N || k >= 10) return;
    float inv = 1.0f / fmaxf(deg[nn], 1.0f);
    float o = s2_b[k] + agg2[nn * 10 + k] * inv;
#pragma unroll
    for (int j = 0; j < 64; ++j) o = fmaf(h1[nn * 64 + j], s2_self[j * 10 + k], o);
    out[nn * 10 + k] = o;
}

extern "C" void kernel_launch(void* const* d_in, const int* in_sizes, int n_in,
                              void* d_out, int out_size, void* d_ws, size_t ws_size,
                              hipStream_t stream)
{
    const float* feat     = (const float*)d_in[0];
    const int*   src      = (const int*)d_in[1];
    const int*   dst      = (const int*)d_in[2];
    const float* conv_w   = (const float*)d_in[3];
    const float* conv_b   = (const float*)d_in[4];
    const float* w1       = (const float*)d_in[5];
    const float* b1       = (const float*)d_in[6];
    const float* w2       = (const float*)d_in[7];
    const float* b2       = (const float*)d_in[8];
    const float* s1_self  = (const float*)d_in[9];
    const float* s1_neigh = (const float*)d_in[10];
    const float* s1_b     = (const float*)d_in[11];
    const float* s2_self  = (const float*)d_in[12];
    const float* s2_neigh = (const float*)d_in[13];
    const float* s2_b     = (const float*)d_in[14];
    float* out = (float*)d_out;

    const int N = in_sizes[0] / 1280;  // 10000
    const int E = in_sizes[1];         // 320000

    // ws layout (floats): deg | agg1(32N) | agg2(10N) | h_cnn(32N) | h1(64N) | z(10N) | w1t(1.31MB)
    float* ws    = (float*)d_ws;
    float* deg   = ws;
    float* agg1  = deg + N;
    float* agg2  = agg1 + (size_t)N * 32;
    float* h_cnn = agg2 + (size_t)N * 10;
    float* h1    = h_cnn + (size_t)N * 32;
    float* z     = h1 + (size_t)N * 64;
    unsigned char* w1t = (unsigned char*)(z + (size_t)N * 10);

    const int zcount = N * 43;  // deg + agg1 + agg2 (contiguous)
    zero_ws<<<(zcount + 255) / 256, 256, 0, stream>>>(ws, zcount);

    w1_prep<<<40, 256, 0, stream>>>(w1, w1t);

    cnn_fused_v3<<<N / 16, 256, 0, stream>>>(feat, conv_w, conv_b, w1t, b1, w2, b2, h_cnn);

    scatter_deg_agg1<<<(int)(((size_t)E * 32 + 255) / 256), 256, 0, stream>>>(src, dst, h_cnn, agg1, deg, E);
    sage1_finish<<<(int)(((size_t)N * 64 + 255) / 256), 256, 0, stream>>>(h_cnn, agg1, deg, s1_self, s1_neigh, s1_b, h1, N);

    sage2_z<<<(int)(((size_t)N * 16 + 255) / 256), 256, 0, stream>>>(h1, s2_neigh, z, N);
    scatter_agg2<<<(int)(((size_t)E * 16 + 255) / 256), 256, 0, stream>>>(src, dst, z, agg2, E);
    sage2_final<<<(int)(((size_t)N * 16 + 255) / 256), 256, 0, stream>>>(h1, agg2, deg, s2_self, s2_b, out, N);
}

// Round 3
// 312.666 us; speedup vs baseline: 2.1511x; 1.4464x over previous
//
#include <hip/hip_runtime.h>

// ---------------------------------------------------------------------------
// GCN pipeline: CNN(conv3x3+relu+pool2x2+FC1+FC2) -> SAGE(mean) -> SAGE(mean)
// Round 3: B (w1) fragments loaded straight from global (fragment-ready,
// pre-swizzled w1f image; L2-resident) -> no B LDS staging, LDS 26 KB,
// 5-6 blocks/CU. A (pooled, hi/lo bf16) in swizzled LDS as before.
// ---------------------------------------------------------------------------

typedef __attribute__((ext_vector_type(8))) short bf16x8;
typedef __attribute__((ext_vector_type(4))) float f32x4;

__device__ __forceinline__ unsigned short f2bf(float v) {
    union { float f; unsigned int u; } x; x.f = v;
    unsigned int r = x.u + 0x7FFFu + ((x.u >> 16) & 1u);  // RNE
    return (unsigned short)(r >> 16);
}
__device__ __forceinline__ float bf2f(unsigned short b) {
    union { float f; unsigned int u; } x; x.u = ((unsigned int)b) << 16;
    return x.f;
}

__global__ __launch_bounds__(256) void zero_ws(float* __restrict__ ws, int count) {
    int i = blockIdx.x * 256 + threadIdx.x;
    if (i < count) ws[i] = 0.0f;
}

// ---------------------------------------------------------------------------
// w1 prep: pack w1 [10240][32] f32 into fragment-ready bf16 hi/lo image.
// Chunk (ph,cq) covers K=256 (8 channels x 32 pooled cols of pooled row ph).
// 16B unit u = part*1024 + (ks*2+jh)*64 + lane  holds 8 bf16:
//   v[vi] = part_of( w1[ (cq*8+ks)*320 + ph*32 + (lane>>4)*8 + vi ][ jh*16 + (lane&15) ] )
// so a wave's 64 lanes load one (ks,jh,part) fragment as 1KB contiguous.
// ---------------------------------------------------------------------------
__global__ __launch_bounds__(256) void w1_prep_v2(
    const float* __restrict__ w1, unsigned char* __restrict__ w1f)
{
    const int chunk = blockIdx.x;          // 0..39
    const int ph = chunk >> 2, cq = chunk & 3;
    const int t = threadIdx.x;
    for (int u = t; u < 2048; u += 256) {
        const int part = u >> 10;
        const int ks   = (u >> 7) & 7;
        const int jh   = (u >> 6) & 1;
        const int lane = u & 63;
        const int j    = jh * 16 + (lane & 15);
        const int c    = cq * 8 + ks;
        const int row0 = c * 320 + ph * 32 + (lane >> 4) * 8;
        unsigned short v[8];
#pragma unroll
        for (int vi = 0; vi < 8; ++vi) {
            float x = w1[(size_t)(row0 + vi) * 32 + j];
            unsigned short h = f2bf(x);
            v[vi] = part ? f2bf(x - bf2f(h)) : h;
        }
        *(uint4*)(w1f + (size_t)chunk * 32768 + (size_t)u * 16) = *(const uint4*)v;
    }
}

// ---------------------------------------------------------------------------
// Fused CNN: 16 nodes/block, 256 threads (4 waves).
// Per chunk (ph 0..9, cq 0..3):
//   - issue 8 coalesced 16B B-fragment loads (global, L2) into regs
//   - conv+pool in regs (thread = (n=t&15, tc=t>>4): 2 pooled cols, 8 ch),
//     write pooled hi/lo bf16 to swizzled LDS A tiles
//   - barrier; wave wv: ksteps {wv, wv+4} x 2 j-halves x 3 split-MFMAs; barrier
// Epilogue: cross-wave reduce, +b1, relu, FC2(+b2), relu -> h_out.
// LDS: Ah 8K + Al 8K + red 8K + h1s 2K = 26 KB.
// ---------------------------------------------------------------------------
__global__ __launch_bounds__(256, 4) void cnn_fused_v4(
    const float* __restrict__ feat,
    const float* __restrict__ conv_w, const float* __restrict__ conv_b,
    const unsigned char* __restrict__ w1f, const float* __restrict__ b1,
    const float* __restrict__ w2, const float* __restrict__ b2,
    float* __restrict__ h_out)
{
    __shared__ __align__(16) unsigned char Ah[8192];   // [16n][256k] bf16, swizzled
    __shared__ __align__(16) unsigned char Al[8192];
    __shared__ float red[4 * 16 * 32];
    __shared__ float h1s[16 * 32];

    const int t = threadIdx.x;
    const int wv = t >> 6;            // wave 0..3
    const int lane = t & 63;
    const int n  = t & 15;            // node within block
    const int tc = t >> 4;            // pooled col pair 0..15
    const int base = blockIdx.x * 16;
    const float* featn = feat + (size_t)(base + n) * 1280;

    f32x4 acc0 = {0.f, 0.f, 0.f, 0.f};
    f32x4 acc1 = {0.f, 0.f, 0.f, 0.f};

    const unsigned int aswz = ((unsigned)(n & 7)) << 4;
    unsigned char* Ahb = Ah + n * 512;
    unsigned char* Alb = Al + n * 512;

    // MFMA frag addressing (per-lane constants)
    const int fn  = lane & 15;            // A row / B col / D col
    const int fkg = lane >> 4;            // k-group
    const unsigned int fa_swz = ((unsigned)(fn & 7)) << 4;
    const unsigned char* fA_hi = Ah + fn * 512;
    const unsigned char* fA_lo = Al + fn * 512;

    for (int ph = 0; ph < 10; ++ph) {
        // ---- load 4x8 input window (rows 2ph-1..2ph+2, cols 4tc-1..4tc+6)
        float w[4][8];
#pragma unroll
        for (int dr = 0; dr < 4; ++dr) {
            int r = 2 * ph - 1 + dr;
            bool rv = (r >= 0) && (r < 20);
            float4 lo = make_float4(0.f, 0.f, 0.f, 0.f);
            float4 mid = lo, hi = lo;
            if (rv) {
                const float* rowp = featn + r * 64;
                mid = *(const float4*)(rowp + 4 * tc);
                if (tc > 0)  lo = *(const float4*)(rowp + 4 * tc - 4);
                if (tc < 15) hi = *(const float4*)(rowp + 4 * tc + 4);
            }
            w[dr][0] = lo.w;
            w[dr][1] = mid.x; w[dr][2] = mid.y; w[dr][3] = mid.z; w[dr][4] = mid.w;
            w[dr][5] = hi.x;  w[dr][6] = hi.y;  w[dr][7] = hi.z;
        }

        for (int cq = 0; cq < 4; ++cq) {
            const int chunk = ph * 4 + cq;

            // ---- B fragments straight from global (coalesced 1KB per load)
            const unsigned char* bsrc = w1f + (size_t)chunk * 32768;
            bf16x8 bfrag[2][2][2];   // [si][jh][part: 0=hi 1=lo]
#pragma unroll
            for (int si = 0; si < 2; ++si) {
                const int ks = wv + 4 * si;
#pragma unroll
                for (int jh = 0; jh < 2; ++jh) {
#pragma unroll
                    for (int part = 0; part < 2; ++part) {
                        bfrag[si][jh][part] = *(const bf16x8*)(
                            bsrc + part * 16384 + (size_t)((ks * 2 + jh) * 64 + lane) * 16);
                    }
                }
            }

            // ---- conv + pool for 8 channels, write A hi/lo (swizzled)
#pragma unroll
            for (int cc = 0; cc < 8; ++cc) {
                const int c = cq * 8 + cc;
                const float* cwp = conv_w + c * 9;   // uniform -> s_load
                float cw0 = cwp[0], cw1 = cwp[1], cw2 = cwp[2];
                float cw3 = cwp[3], cw4 = cwp[4], cw5 = cwp[5];
                float cw6 = cwp[6], cw7 = cwp[7], cw8 = cwp[8];
                float cb = conv_b[c];
                float s[2][4];
#pragma unroll
                for (int a = 0; a < 2; ++a) {
#pragma unroll
                    for (int x = 0; x < 4; ++x) {
                        float acc = cb;
                        acc = fmaf(w[a+0][x+0], cw0, acc);
                        acc = fmaf(w[a+0][x+1], cw1, acc);
                        acc = fmaf(w[a+0][x+2], cw2, acc);
                        acc = fmaf(w[a+1][x+0], cw3, acc);
                        acc = fmaf(w[a+1][x+1], cw4, acc);
                        acc = fmaf(w[a+1][x+2], cw5, acc);
                        acc = fmaf(w[a+2][x+0], cw6, acc);
                        acc = fmaf(w[a+2][x+1], cw7, acc);
                        acc = fmaf(w[a+2][x+2], cw8, acc);
                        s[a][x] = acc;
                    }
                }
                float p0 = fmaxf(fmaxf(fmaxf(s[0][0], s[0][1]), fmaxf(s[1][0], s[1][1])), 0.f);
                float p1 = fmaxf(fmaxf(fmaxf(s[0][2], s[0][3]), fmaxf(s[1][2], s[1][3])), 0.f);
                unsigned short h0 = f2bf(p0), h1 = f2bf(p1);
                unsigned short l0 = f2bf(p0 - bf2f(h0)), l1 = f2bf(p1 - bf2f(h1));
                unsigned int byt = ((unsigned)(cc * 64 + 4 * tc)) ^ aswz;
                *(unsigned int*)(Ahb + byt) = ((unsigned)h1 << 16) | h0;
                *(unsigned int*)(Alb + byt) = ((unsigned)l1 << 16) | l0;
            }

            __syncthreads();

            // ---- MFMA: wave wv handles ksteps {wv, wv+4}
#pragma unroll
            for (int si = 0; si < 2; ++si) {
                const int ks = wv + 4 * si;
                const unsigned int koff = (unsigned)(ks * 64 + fkg * 16);
                bf16x8 a_hi = *(const bf16x8*)(fA_hi + (koff ^ fa_swz));
                bf16x8 a_lo = *(const bf16x8*)(fA_lo + (koff ^ fa_swz));
                acc0 = __builtin_amdgcn_mfma_f32_16x16x32_bf16(a_lo, bfrag[si][0][0], acc0, 0, 0, 0);
                acc0 = __builtin_amdgcn_mfma_f32_16x16x32_bf16(a_hi, bfrag[si][0][1], acc0, 0, 0, 0);
                acc0 = __builtin_amdgcn_mfma_f32_16x16x32_bf16(a_hi, bfrag[si][0][0], acc0, 0, 0, 0);
                acc1 = __builtin_amdgcn_mfma_f32_16x16x32_bf16(a_lo, bfrag[si][1][0], acc1, 0, 0, 0);
                acc1 = __builtin_amdgcn_mfma_f32_16x16x32_bf16(a_hi, bfrag[si][1][1], acc1, 0, 0, 0);
                acc1 = __builtin_amdgcn_mfma_f32_16x16x32_bf16(a_hi, bfrag[si][1][0], acc1, 0, 0, 0);
            }

            __syncthreads();
        }
    }

    // ---- cross-wave reduction of partial FC1, bias, relu, FC2, relu
#pragma unroll
    for (int r = 0; r < 4; ++r) {
        int row = (lane >> 4) * 4 + r;   // node
        red[wv * 512 + row * 32 + fn]      = acc0[r];
        red[wv * 512 + row * 32 + 16 + fn] = acc1[r];
    }
    __syncthreads();

    {
        const int en = t >> 4, jp = t & 15;
        const int j0 = 2 * jp;
        float2 bv = *(const float2*)(b1 + j0);
        float s0 = bv.x, s1 = bv.y;
#pragma unroll
        for (int wi = 0; wi < 4; ++wi) {
            s0 += red[wi * 512 + en * 32 + j0];
            s1 += red[wi * 512 + en * 32 + j0 + 1];
        }
        s0 = fmaxf(s0, 0.f); s1 = fmaxf(s1, 0.f);
        h1s[en * 32 + j0] = s0;
        h1s[en * 32 + j0 + 1] = s1;
    }
    __syncthreads();
    {
        const int en = t >> 4, jp = t & 15;
        const int j0 = 2 * jp;
        float2 bv = *(const float2*)(b2 + j0);
        float o0 = bv.x, o1 = bv.y;
#pragma unroll
        for (int k = 0; k < 32; ++k) {
            float h = h1s[en * 32 + k];
            float2 wv2 = *(const float2*)(w2 + k * 32 + j0);
            o0 = fmaf(h, wv2.x, o0);
            o1 = fmaf(h, wv2.y, o1);
        }
        o0 = fmaxf(o0, 0.f); o1 = fmaxf(o1, 0.f);
        *(float2*)(h_out + (size_t)(base + en) * 32 + j0) = make_float2(o0, o1);
    }
}

// --------------------------- SAGE layers -----------------------------------
__global__ __launch_bounds__(256) void scatter_deg_agg1(
    const int* __restrict__ src, const int* __restrict__ dst,
    const float* __restrict__ h, float* __restrict__ agg1, float* __restrict__ deg, int E)
{
    int tid = blockIdx.x * 256 + threadIdx.x;
    int e = tid >> 5, j = tid & 31;
    if (e >= E) return;
    int s = src[e], d = dst[e];
    atomicAdd(&agg1[d * 32 + j], h[s * 32 + j]);
    if (j == 0) atomicAdd(&deg[d], 1.0f);
}

__global__ __launch_bounds__(256) void sage1_finish(
    const float* __restrict__ h, const float* __restrict__ agg1, const float* __restrict__ deg,
    const float* __restrict__ s1_self, const float* __restrict__ s1_neigh,
    const float* __restrict__ s1_b, float* __restrict__ h1, int N)
{
    int tid = blockIdx.x * 256 + threadIdx.x;
    int nn = tid >> 6, k = tid & 63;
    if (nn >= N) return;
    float inv = 1.0f / fmaxf(deg[nn], 1.0f);
    float o = s1_b[k];
#pragma unroll
    for (int j = 0; j < 32; ++j) {
        o = fmaf(h[nn * 32 + j], s1_self[j * 64 + k], o);
        o = fmaf(agg1[nn * 32 + j] * inv, s1_neigh[j * 64 + k], o);
    }
    h1[nn * 64 + k] = fmaxf(o, 0.0f);
}

__global__ __launch_bounds__(256) void sage2_z(
    const float* __restrict__ h1, const float* __restrict__ s2_neigh,
    float* __restrict__ z, int N)
{
    int tid = blockIdx.x * 256 + threadIdx.x;
    int nn = tid >> 4, k = tid & 15;
    if (nn >= N || k >= 10) return;
    float o = 0.0f;
#pragma unroll
    for (int j = 0; j < 64; ++j) o = fmaf(h1[nn * 64 + j], s2_neigh[j * 10 + k], o);
    z[nn * 10 + k] = o;
}

__global__ __launch_bounds__(256) void scatter_agg2(
    const int* __restrict__ src, const int* __restrict__ dst,
    const float* __restrict__ z, float* __restrict__ agg2, int E)
{
    int tid = blockIdx.x * 256 + threadIdx.x;
    int e = tid >> 4, k = tid & 15;
    if (e >= E || k >= 10) return;
    atomicAdd(&agg2[dst[e] * 10 + k], z[src[e] * 10 + k]);
}

__global__ __launch_bounds__(256) void sage2_final(
    const float* __restrict__ h1, const float* __restrict__ agg2, const float* __restrict__ deg,
    const float* __restrict__ s2_self, const float* __restrict__ s2_b,
    float* __restrict__ out, int N)
{
    int tid = blockIdx.x * 256 + threadIdx.x;
    int nn = tid >> 4, k = tid & 15;
    if (nn >= N || k >= 10) return;
    float inv = 1.0f / fmaxf(deg[nn], 1.0f);
    float o = s2_b[k] + agg2[nn * 10 + k] * inv;
#pragma unroll
    for (int j = 0; j < 64; ++j) o = fmaf(h1[nn * 64 + j], s2_self[j * 10 + k], o);
    out[nn * 10 + k] = o;
}

extern "C" void kernel_launch(void* const* d_in, const int* in_sizes, int n_in,
                              void* d_out, int out_size, void* d_ws, size_t ws_size,
                              hipStream_t stream)
{
    const float* feat     = (const float*)d_in[0];
    const int*   src      = (const int*)d_in[1];
    const int*   dst      = (const int*)d_in[2];
    const float* conv_w   = (const float*)d_in[3];
    const float* conv_b   = (const float*)d_in[4];
    const float* w1       = (const float*)d_in[5];
    const float* b1       = (const float*)d_in[6];
    const float* w2       = (const float*)d_in[7];
    const float* b2       = (const float*)d_in[8];
    const float* s1_self  = (const float*)d_in[9];
    const float* s1_neigh = (const float*)d_in[10];
    const float* s1_b     = (const float*)d_in[11];
    const float* s2_self  = (const float*)d_in[12];
    const float* s2_neigh = (const float*)d_in[13];
    const float* s2_b     = (const float*)d_in[14];
    float* out = (float*)d_out;

    const int N = in_sizes[0] / 1280;  // 10000
    const int E = in_sizes[1];         // 320000

    // ws layout (floats): deg | agg1(32N) | agg2(10N) | h_cnn(32N) | h1(64N) | z(10N) | w1f(1.31MB)
    float* ws    = (float*)d_ws;
    float* deg   = ws;
    float* agg1  = deg + N;
    float* agg2  = agg1 + (size_t)N * 32;
    float* h_cnn = agg2 + (size_t)N * 10;
    float* h1    = h_cnn + (size_t)N * 32;
    float* z     = h1 + (size_t)N * 64;
    unsigned char* w1f = (unsigned char*)(z + (size_t)N * 10);

    const int zcount = N * 43;  // deg + agg1 + agg2 (contiguous)
    zero_ws<<<(zcount + 255) / 256, 256, 0, stream>>>(ws, zcount);

    w1_prep_v2<<<40, 256, 0, stream>>>(w1, w1f);

    cnn_fused_v4<<<N / 16, 256, 0, stream>>>(feat, conv_w, conv_b, w1f, b1, w2, b2, h_cnn);

    scatter_deg_agg1<<<(int)(((size_t)E * 32 + 255) / 256), 256, 0, stream>>>(src, dst, h_cnn, agg1, deg, E);
    sage1_finish<<<(int)(((size_t)N * 64 + 255) / 256), 256, 0, stream>>>(h_cnn, agg1, deg, s1_self, s1_neigh, s1_b, h1, N);

    sage2_z<<<(int)(((size_t)N * 16 + 255) / 256), 256, 0, stream>>>(h1, s2_neigh, z, N);
    scatter_agg2<<<(int)(((size_t)E * 16 + 255) / 256), 256, 0, stream>>>(src, dst, z, agg2, E);
    sage2_final<<<(int)(((size_t)N * 16 + 255) / 256), 256, 0, stream>>>(h1, agg2, deg, s2_self, s2_b, out, N);
}

// Round 4
// 273.602 us; speedup vs baseline: 2.4583x; 1.1428x over previous
//
#include <hip/hip_runtime.h>

// ---------------------------------------------------------------------------
// GCN pipeline: CNN(conv3x3+relu+pool2x2+FC1+FC2) -> SAGE(mean) -> SAGE(mean)
// Round 4: conv ALSO on MFMA (im2col 32x32x16 bf16 hi/lo, K=9 padded to 16).
//   - im2col rows ordered as pool-quads: row = 4*quad + corner, so the 32x32
//     D-layout gives each lane the 4 corners of one quad in regs -> pool is
//     in-lane. Pooled -> hi/lo bf16 -> shfl/perm repack -> b128 into FC1-A.
//   - FC1 B-frags fragment-ready in global (w1f), A in LDS (node-swizzled).
//   - 16 nodes/block, 4 waves; wave owns 4 nodes for conv; FC1 shared.
// ---------------------------------------------------------------------------

typedef __attribute__((ext_vector_type(8)))  short bf16x8;
typedef __attribute__((ext_vector_type(4)))  float f32x4;
typedef __attribute__((ext_vector_type(16))) float f32x16;

__device__ __forceinline__ unsigned short f2bf(float v) {
    union { float f; unsigned int u; } x; x.f = v;
    unsigned int r = x.u + 0x7FFFu + ((x.u >> 16) & 1u);  // RNE
    return (unsigned short)(r >> 16);
}
__device__ __forceinline__ float bf2f(unsigned short b) {
    union { float f; unsigned int u; } x; x.u = ((unsigned int)b) << 16;
    return x.f;
}

__global__ __launch_bounds__(256) void zero_ws(float* __restrict__ ws, int count) {
    int i = blockIdx.x * 256 + threadIdx.x;
    if (i < count) ws[i] = 0.0f;
}

// ---------------------------------------------------------------------------
// w1 prep: fragment-ready bf16 hi/lo image, per quarter (ph,qq: 8 pooled cols).
// unit u = ((ks*2+jh)*2+part)*64 + lane holds 8 bf16:
//   v[i] = part_of( w1[ c*320 + ph*32 + qq*8 + i ][ jh*16 + (lane&15) ] ),
//   c = ks*4 + (lane>>4).   (k' = c*8 + qit, qit = i)
// ---------------------------------------------------------------------------
__global__ __launch_bounds__(256) void w1_prep_v3(
    const float* __restrict__ w1, unsigned char* __restrict__ w1f)
{
    const int quarter = blockIdx.x;          // 0..39 = ph*4+qq
    const int ph = quarter >> 2, qq = quarter & 3;
    const int t = threadIdx.x;
    for (int u = t; u < 2048; u += 256) {
        const int ks   = u >> 8;
        const int jh   = (u >> 7) & 1;
        const int part = (u >> 6) & 1;
        const int lane = u & 63;
        const int j    = jh * 16 + (lane & 15);
        const int c    = ks * 4 + (lane >> 4);
        const int k0   = c * 320 + ph * 32 + qq * 8;
        unsigned short v[8];
#pragma unroll
        for (int i = 0; i < 8; ++i) {
            float x = w1[(size_t)(k0 + i) * 32 + j];
            unsigned short h = f2bf(x);
            v[i] = part ? f2bf(x - bf2f(h)) : h;
        }
        *(uint4*)(w1f + (size_t)quarter * 32768 + (size_t)u * 16) = *(const uint4*)v;
    }
}

// ---------------------------------------------------------------------------
// Fused CNN v5. LDS: convA 32KB ([wv4][nn4][part2][kg2][row32 xor-swz][16B])
//                 + fc1A 16KB ([part2][node16][unit32 ^ node-swz][16B]) = 48KB
// Per quarter (ph,qq): im2col (per-lane 12 feat loads, 2 A-rows hi/lo)
//   -> conv MFMA 32x32x16 per node (same-wave LDS, no barrier)
//   -> in-lane pool+bias+relu -> shfl/perm repack -> b128 into fc1A
//   -> barrier -> FC1 16x16x32 (2 ks x 2 jh x 3 split) -> barrier.
// ---------------------------------------------------------------------------
__global__ __launch_bounds__(256, 3) void cnn_fused_v5(
    const float* __restrict__ feat,
    const float* __restrict__ conv_w, const float* __restrict__ conv_b,
    const unsigned char* __restrict__ w1f, const float* __restrict__ b1,
    const float* __restrict__ w2, const float* __restrict__ b2,
    float* __restrict__ h_out)
{
    __shared__ __align__(16) unsigned char convA[32768];
    __shared__ __align__(16) unsigned char fc1A[16384];

    const int t = threadIdx.x;
    const int wv = t >> 6;
    const int lane = t & 63;
    const int base = blockIdx.x * 16;

    // im2col role
    const int nn  = lane >> 4;        // node-in-wave 0..3
    const int lc  = lane & 15;
    const int pwl = lc & 7;           // pooled col within quarter
    const int aa  = lc >> 3;          // corner row a (0/1)
    const float* featn = feat + (size_t)(base + wv * 4 + nn) * 1280;

    // conv MFMA roles
    const int cch = lane & 31;        // channel (B col / D col)
    const int ckg = lane >> 5;
    const int rowr = lane & 31;       // A-frag row
    const int rswr = rowr ^ ((rowr >> 3) & 3);

    // conv weight fragments (constant): K=16, taps 0..8 used
    bf16x8 cbh, cbl;
    {
        union { unsigned short u[8]; bf16x8 v; } H, L;
#pragma unroll
        for (int i = 0; i < 8; ++i) {
            int k = ckg * 8 + i;
            float x = (k < 9) ? conv_w[cch * 9 + k] : 0.0f;
            unsigned short h = f2bf(x);
            H.u[i] = h; L.u[i] = f2bf(x - bf2f(h));
        }
        cbh = H.v; cbl = L.v;
    }
    const float cbias = conv_b[cch];

    // FC1 frag addressing
    const int nfr = lane & 15, kg16 = lane >> 4;
    const unsigned int nsw = (unsigned)((nfr & 7) << 4);

    f32x4 acc0 = {0.f, 0.f, 0.f, 0.f};
    f32x4 acc1 = {0.f, 0.f, 0.f, 0.f};

    // zero convA once (k9..15 stay zero forever; k0..8 overwritten each quarter)
    {
        uint4 z = make_uint4(0, 0, 0, 0);
#pragma unroll
        for (int i = 0; i < 8; ++i)
            *(uint4*)&convA[(t + 256 * i) * 16] = z;
    }
    __syncthreads();

#pragma unroll 1
    for (int ph = 0; ph < 10; ++ph) {
#pragma unroll 1
        for (int qq = 0; qq < 4; ++qq) {
            const int quarter = ph * 4 + qq;

            // ---- (1) FC1 B-frags from global (L2), consumed after barrier
            const unsigned char* wq = w1f + (size_t)quarter * 32768;
            bf16x8 bF[2][2][2];
#pragma unroll
            for (int si = 0; si < 2; ++si)
#pragma unroll
                for (int jh = 0; jh < 2; ++jh)
#pragma unroll
                    for (int part = 0; part < 2; ++part)
                        bF[si][jh][part] = *(const bf16x8*)(
                            wq + (size_t)(((((wv + si * 4) * 2 + jh) * 2 + part)) << 10) + lane * 16);

            // ---- (2) im2col: 3x4 window, 2 A-rows (corners aa*2+{0,1})
            const int pw = qq * 8 + pwl;
            float f[3][4];
#pragma unroll
            for (int di = 0; di < 3; ++di) {
                int r = 2 * ph - 1 + aa + di;
                bool rv = (r >= 0) && (r < 20);
                int rc = rv ? r : 0;
#pragma unroll
                for (int dj = 0; dj < 4; ++dj) {
                    int c = 2 * pw - 1 + dj;
                    bool cv = (c >= 0) && (c < 64);
                    int ccl = cv ? c : 0;
                    float v = featn[rc * 64 + ccl];
                    f[di][dj] = (rv && cv) ? v : 0.0f;
                }
            }
            unsigned char* abw = convA + wv * 8192 + nn * 2048;
#pragma unroll
            for (int b = 0; b < 2; ++b) {
                int row = pwl * 4 + aa * 2 + b;
                int rsw = row ^ ((row >> 3) & 3);
                unsigned short h[9], l[9];
#pragma unroll
                for (int k = 0; k < 9; ++k) {
                    float x = f[k / 3][b + (k % 3)];
                    h[k] = f2bf(x);
                    l[k] = f2bf(x - bf2f(h[k]));
                }
                uint4 H = make_uint4(h[0] | ((unsigned)h[1] << 16), h[2] | ((unsigned)h[3] << 16),
                                     h[4] | ((unsigned)h[5] << 16), h[6] | ((unsigned)h[7] << 16));
                uint4 L = make_uint4(l[0] | ((unsigned)l[1] << 16), l[2] | ((unsigned)l[3] << 16),
                                     l[4] | ((unsigned)l[5] << 16), l[6] | ((unsigned)l[7] << 16));
                *(uint4*)(abw + rsw * 16) = H;                       // part0 kg0
                *(unsigned short*)(abw + 512 + rsw * 16) = h[8];     // part0 kg1 (k8)
                *(uint4*)(abw + 1024 + rsw * 16) = L;                // part1 kg0
                *(unsigned short*)(abw + 1536 + rsw * 16) = l[8];    // part1 kg1
            }

            // ---- (3) conv MFMA + in-lane pool + repack into fc1A (same wave)
#pragma unroll
            for (int nn2 = 0; nn2 < 4; ++nn2) {
                const unsigned char* ab = convA + wv * 8192 + nn2 * 2048;
                bf16x8 a_h = *(const bf16x8*)(ab + ckg * 512 + rswr * 16);
                bf16x8 a_l = *(const bf16x8*)(ab + 1024 + ckg * 512 + rswr * 16);
                f32x16 ca = {};
                ca = __builtin_amdgcn_mfma_f32_32x32x16_bf16(a_l, cbh, ca, 0, 0, 0);
                ca = __builtin_amdgcn_mfma_f32_32x32x16_bf16(a_h, cbl, ca, 0, 0, 0);
                ca = __builtin_amdgcn_mfma_f32_32x32x16_bf16(a_h, cbh, ca, 0, 0, 0);

                float pv0 = fmaxf(fmaxf(fmaxf(ca[0],  ca[1]),  fmaxf(ca[2],  ca[3]))  + cbias, 0.f);
                float pv1 = fmaxf(fmaxf(fmaxf(ca[4],  ca[5]),  fmaxf(ca[6],  ca[7]))  + cbias, 0.f);
                float pv2 = fmaxf(fmaxf(fmaxf(ca[8],  ca[9]),  fmaxf(ca[10], ca[11])) + cbias, 0.f);
                float pv3 = fmaxf(fmaxf(fmaxf(ca[12], ca[13]), fmaxf(ca[14], ca[15])) + cbias, 0.f);

                unsigned short h0 = f2bf(pv0), h1 = f2bf(pv1), h2 = f2bf(pv2), h3 = f2bf(pv3);
                unsigned short l0 = f2bf(pv0 - bf2f(h0)), l1 = f2bf(pv1 - bf2f(h1));
                unsigned short l2 = f2bf(pv2 - bf2f(h2)), l3 = f2bf(pv3 - bf2f(h3));
                unsigned int ha = h0 | ((unsigned)h1 << 16), hb = h2 | ((unsigned)h3 << 16);
                unsigned int la = l0 | ((unsigned)l1 << 16), lb = l2 | ((unsigned)l3 << 16);
                unsigned int pha = (unsigned)__shfl_xor((int)ha, 32);
                unsigned int phb = (unsigned)__shfl_xor((int)hb, 32);
                unsigned int pla = (unsigned)__shfl_xor((int)la, 32);
                unsigned int plb = (unsigned)__shfl_xor((int)lb, 32);
                bool hih = (lane < 32);
                unsigned int q0 = hih ? pha : la;
                unsigned int q1 = hih ? ha  : pla;
                unsigned int q2 = hih ? phb : lb;
                unsigned int q3 = hih ? hb  : plb;
                unsigned int w0 = __builtin_amdgcn_perm(q0, q1, 0x05040100u);
                unsigned int w1v = __builtin_amdgcn_perm(q0, q1, 0x07060302u);
                unsigned int w2v = __builtin_amdgcn_perm(q2, q3, 0x05040100u);
                unsigned int w3v = __builtin_amdgcn_perm(q2, q3, 0x07060302u);
                int nloc = wv * 4 + nn2;
                unsigned int off = (hih ? 0u : 8192u) + (unsigned)(nloc * 512)
                                 + (((unsigned)cch * 16u) ^ (unsigned)((nloc & 7) << 4));
                *(uint4*)&fc1A[off] = make_uint4(w0, w1v, w2v, w3v);
            }

            __syncthreads();

            // ---- (4) FC1 MFMA: ks = wv, wv+4
#pragma unroll
            for (int si = 0; si < 2; ++si) {
                int ks = wv + si * 4;
                unsigned int ao = ((unsigned)(ks * 64 + kg16 * 16)) ^ nsw;
                bf16x8 fa_h = *(const bf16x8*)&fc1A[nfr * 512 + ao];
                bf16x8 fa_l = *(const bf16x8*)&fc1A[8192 + nfr * 512 + ao];
                acc0 = __builtin_amdgcn_mfma_f32_16x16x32_bf16(fa_l, bF[si][0][0], acc0, 0, 0, 0);
                acc0 = __builtin_amdgcn_mfma_f32_16x16x32_bf16(fa_h, bF[si][0][1], acc0, 0, 0, 0);
                acc0 = __builtin_amdgcn_mfma_f32_16x16x32_bf16(fa_h, bF[si][0][0], acc0, 0, 0, 0);
                acc1 = __builtin_amdgcn_mfma_f32_16x16x32_bf16(fa_l, bF[si][1][0], acc1, 0, 0, 0);
                acc1 = __builtin_amdgcn_mfma_f32_16x16x32_bf16(fa_h, bF[si][1][1], acc1, 0, 0, 0);
                acc1 = __builtin_amdgcn_mfma_f32_16x16x32_bf16(fa_h, bF[si][1][0], acc1, 0, 0, 0);
            }

            __syncthreads();
        }
    }

    // ---- epilogue: cross-wave reduce (overlay on convA), +b1, relu, FC2, relu
    float* red = (float*)convA;            // 8KB
    float* h1s = (float*)(convA + 8192);   // 2KB
#pragma unroll
    for (int r = 0; r < 4; ++r) {
        int node = (lane >> 4) * 4 + r;
        red[wv * 512 + node * 32 + (lane & 15)]      = acc0[r];
        red[wv * 512 + node * 32 + 16 + (lane & 15)] = acc1[r];
    }
    __syncthreads();
    {
        const int en = t >> 4, jp = t & 15;
        const int j0 = 2 * jp;
        float2 bv = *(const float2*)(b1 + j0);
        float s0 = bv.x, s1 = bv.y;
#pragma unroll
        for (int wi = 0; wi < 4; ++wi) {
            s0 += red[wi * 512 + en * 32 + j0];
            s1 += red[wi * 512 + en * 32 + j0 + 1];
        }
        s0 = fmaxf(s0, 0.f); s1 = fmaxf(s1, 0.f);
        h1s[en * 32 + j0] = s0;
        h1s[en * 32 + j0 + 1] = s1;
    }
    __syncthreads();
    {
        const int en = t >> 4, jp = t & 15;
        const int j0 = 2 * jp;
        float2 bv = *(const float2*)(b2 + j0);
        float o0 = bv.x, o1 = bv.y;
#pragma unroll
        for (int k = 0; k < 32; ++k) {
            float h = h1s[en * 32 + k];
            float2 wv2 = *(const float2*)(w2 + k * 32 + j0);
            o0 = fmaf(h, wv2.x, o0);
            o1 = fmaf(h, wv2.y, o1);
        }
        o0 = fmaxf(o0, 0.f); o1 = fmaxf(o1, 0.f);
        *(float2*)(h_out + (size_t)(base + en) * 32 + j0) = make_float2(o0, o1);
    }
}

// --------------------------- SAGE layers (unchanged) -----------------------
__global__ __launch_bounds__(256) void scatter_deg_agg1(
    const int* __restrict__ src, const int* __restrict__ dst,
    const float* __restrict__ h, float* __restrict__ agg1, float* __restrict__ deg, int E)
{
    int tid = blockIdx.x * 256 + threadIdx.x;
    int e = tid >> 5, j = tid & 31;
    if (e >= E) return;
    int s = src[e], d = dst[e];
    atomicAdd(&agg1[d * 32 + j], h[s * 32 + j]);
    if (j == 0) atomicAdd(&deg[d], 1.0f);
}

__global__ __launch_bounds__(256) void sage1_finish(
    const float* __restrict__ h, const float* __restrict__ agg1, const float* __restrict__ deg,
    const float* __restrict__ s1_self, const float* __restrict__ s1_neigh,
    const float* __restrict__ s1_b, float* __restrict__ h1, int N)
{
    int tid = blockIdx.x * 256 + threadIdx.x;
    int nn = tid >> 6, k = tid & 63;
    if (nn >= N) return;
    float inv = 1.0f / fmaxf(deg[nn], 1.0f);
    float o = s1_b[k];
#pragma unroll
    for (int j = 0; j < 32; ++j) {
        o = fmaf(h[nn * 32 + j], s1_self[j * 64 + k], o);
        o = fmaf(agg1[nn * 32 + j] * inv, s1_neigh[j * 64 + k], o);
    }
    h1[nn * 64 + k] = fmaxf(o, 0.0f);
}

__global__ __launch_bounds__(256) void sage2_z(
    const float* __restrict__ h1, const float* __restrict__ s2_neigh,
    float* __restrict__ z, int N)
{
    int tid = blockIdx.x * 256 + threadIdx.x;
    int nn = tid >> 4, k = tid & 15;
    if (nn >= N || k >= 10) return;
    float o = 0.0f;
#pragma unroll
    for (int j = 0; j < 64; ++j) o = fmaf(h1[nn * 64 + j], s2_neigh[j * 10 + k], o);
    z[nn * 10 + k] = o;
}

__global__ __launch_bounds__(256) void scatter_agg2(
    const int* __restrict__ src, const int* __restrict__ dst,
    const float* __restrict__ z, float* __restrict__ agg2, int E)
{
    int tid = blockIdx.x * 256 + threadIdx.x;
    int e = tid >> 4, k = tid & 15;
    if (e >= E || k >= 10) return;
    atomicAdd(&agg2[dst[e] * 10 + k], z[src[e] * 10 + k]);
}

__global__ __launch_bounds__(256) void sage2_final(
    const float* __restrict__ h1, const float* __restrict__ agg2, const float* __restrict__ deg,
    const float* __restrict__ s2_self, const float* __restrict__ s2_b,
    float* __restrict__ out, int N)
{
    int tid = blockIdx.x * 256 + threadIdx.x;
    int nn = tid >> 4, k = tid & 15;
    if (nn >= N || k >= 10) return;
    float inv = 1.0f / fmaxf(deg[nn], 1.0f);
    float o = s2_b[k] + agg2[nn * 10 + k] * inv;
#pragma unroll
    for (int j = 0; j < 64; ++j) o = fmaf(h1[nn * 64 + j], s2_self[j * 10 + k], o);
    out[nn * 10 + k] = o;
}

extern "C" void kernel_launch(void* const* d_in, const int* in_sizes, int n_in,
                              void* d_out, int out_size, void* d_ws, size_t ws_size,
                              hipStream_t stream)
{
    const float* feat     = (const float*)d_in[0];
    const int*   src      = (const int*)d_in[1];
    const int*   dst      = (const int*)d_in[2];
    const float* conv_w   = (const float*)d_in[3];
    const float* conv_b   = (const float*)d_in[4];
    const float* w1       = (const float*)d_in[5];
    const float* b1       = (const float*)d_in[6];
    const float* w2       = (const float*)d_in[7];
    const float* b2       = (const float*)d_in[8];
    const float* s1_self  = (const float*)d_in[9];
    const float* s1_neigh = (const float*)d_in[10];
    const float* s1_b     = (const float*)d_in[11];
    const float* s2_self  = (const float*)d_in[12];
    const float* s2_neigh = (const float*)d_in[13];
    const float* s2_b     = (const float*)d_in[14];
    float* out = (float*)d_out;

    const int N = in_sizes[0] / 1280;  // 10000
    const int E = in_sizes[1];         // 320000

    // ws layout (floats): deg | agg1(32N) | agg2(10N) | h_cnn(32N) | h1(64N) | z(10N) | w1f(1.31MB)
    float* ws    = (float*)d_ws;
    float* deg   = ws;
    float* agg1  = deg + N;
    float* agg2  = agg1 + (size_t)N * 32;
    float* h_cnn = agg2 + (size_t)N * 10;
    float* h1    = h_cnn + (size_t)N * 32;
    float* z     = h1 + (size_t)N * 64;
    unsigned char* w1f = (unsigned char*)(z + (size_t)N * 10);

    const int zcount = N * 43;  // deg + agg1 + agg2 (contiguous)
    zero_ws<<<(zcount + 255) / 256, 256, 0, stream>>>(ws, zcount);

    w1_prep_v3<<<40, 256, 0, stream>>>(w1, w1f);

    cnn_fused_v5<<<N / 16, 256, 0, stream>>>(feat, conv_w, conv_b, w1f, b1, w2, b2, h_cnn);

    scatter_deg_agg1<<<(int)(((size_t)E * 32 + 255) / 256), 256, 0, stream>>>(src, dst, h_cnn, agg1, deg, E);
    sage1_finish<<<(int)(((size_t)N * 64 + 255) / 256), 256, 0, stream>>>(h_cnn, agg1, deg, s1_self, s1_neigh, s1_b, h1, N);

    sage2_z<<<(int)(((size_t)N * 16 + 255) / 256), 256, 0, stream>>>(h1, s2_neigh, z, N);
    scatter_agg2<<<(int)(((size_t)E * 16 + 255) / 256), 256, 0, stream>>>(src, dst, z, agg2, E);
    sage2_final<<<(int)(((size_t)N * 16 + 255) / 256), 256, 0, stream>>>(h1, agg2, deg, s2_self, s2_b, out, N);
}